// Round 8
// baseline (200.358 us; speedup 1.0000x reference)
//
#include <hip/hip_runtime.h>

#define H_IN   128
#define W_IN   128
#define HW_IN  16384
#define C_IN   256
#define CC     64
#define HO     64
#define WO     64
#define HWO    4096
#define NB     4
#define NPX    16384   // B*HWO output pixels
#define NCHP   48      // padded encoder out channels (25 mask + 16 kenc + 7 pad)
#define NPH    16      // encoder ci-phases (4 ci each)

// workspace layout (float element offsets)
#define OFF_WC    0            // 8*256*8    = 16384     compress W [ccg][c][8]
#define OFF_WE    16384        // 576*48     = 27648     encoder W [ci*9+t][48ch]
#define OFF_CX    44032        // 4*64*16384 = 4194304
#define OFF_PART  4238336      // 16*48*16384 = 12582912  partials [ph][ch][px]
#define OFF_MASK  16821248     // 25*16384   = 409600    mask [k][px]
#define OFF_RED   17230848     // 48*16384   = 786432    reduced [ch][px]
// total 18017280 floats = 72.1 MB

__global__ __launch_bounds__(256) void prep_kernel(
    const float* __restrict__ wc, const float* __restrict__ we,
    const float* __restrict__ wk, float* __restrict__ ws) {
  int i = blockIdx.x * 256 + threadIdx.x;   // 44032 threads
  if (i < 16384) {
    int ccg = i >> 11, c = (i >> 3) & 255, j = i & 7;
    ws[OFF_WC + i] = wc[(ccg * 8 + j) * C_IN + c];
  } else if (i < 44032) {
    int e = i - 16384;                      // < 27648
    int row = e / 48, ch = e - row * 48;    // row = ci*9 + (kh*3+kw)
    float v = 0.f;
    if (ch < 25)      v = we[ch * 576 + row];
    else if (ch < 41) v = wk[(ch - 25) * 576 + row];
    ws[OFF_WE + e] = v;
  }
}

// 1x1 conv as GEMM: 16 waves = (ccg 8 x kh 2); thread = 2 px x 8 cc.
// Grid 512 (128 px/block) -> 2 blocks/CU -> 32 waves/CU.
__global__ __launch_bounds__(1024) void compress_kernel(
    const float* __restrict__ x, const float* __restrict__ bcomp,
    const float* __restrict__ wsr, float* __restrict__ cx) {
  __shared__ float red[8][64][17];   // 34.8 KB; odd stride -> conflict-free
  int tid = threadIdx.x;
  int wv = tid >> 6, lane = tid & 63;
  int ccg = __builtin_amdgcn_readfirstlane(wv & 7);
  int kh  = __builtin_amdgcn_readfirstlane(wv >> 3);
  int pxbase = blockIdx.x * 128;          // block covers 128 px, within one b
  int b = pxbase >> 14;
  int p = (pxbase & (HW_IN - 1)) + lane * 2;
  const float* xb = x + (size_t)b * C_IN * HW_IN + p;
  const float* wp = wsr + OFF_WC + ccg * (256 * 8);
  float2 acc[8];
#pragma unroll
  for (int j = 0; j < 8; ++j) acc[j] = make_float2(0.f, 0.f);
  int cbase = kh * 128;
  float2 xv[4], xn[4];
#pragma unroll
  for (int u = 0; u < 4; ++u)
    xv[u] = *(const float2*)(xb + (size_t)(cbase + u) * HW_IN);
  for (int c0 = 0; c0 < 128; c0 += 4) {
    if (c0 + 4 < 128) {
#pragma unroll
      for (int u = 0; u < 4; ++u)
        xn[u] = *(const float2*)(xb + (size_t)(cbase + c0 + 4 + u) * HW_IN);
    }
#pragma unroll
    for (int u = 0; u < 4; ++u) {
      const float* wrow = wp + (cbase + c0 + u) * 8;  // uniform -> s_load
      float2 xu = xv[u];
#pragma unroll
      for (int j = 0; j < 8; ++j) {
        float wj = wrow[j];
        acc[j].x = fmaf(wj, xu.x, acc[j].x);
        acc[j].y = fmaf(wj, xu.y, acc[j].y);
      }
    }
#pragma unroll
    for (int u = 0; u < 4; ++u) xv[u] = xn[u];
  }
  if (kh == 1) {
    float* d = &red[ccg][lane][0];
#pragma unroll
    for (int j = 0; j < 8; ++j) {
      d[j * 2 + 0] = acc[j].x; d[j * 2 + 1] = acc[j].y;
    }
  }
  __syncthreads();
  if (kh == 0) {
    const float* d = &red[ccg][lane][0];
#pragma unroll
    for (int j = 0; j < 8; ++j) {
      int cc = ccg * 8 + j;
      float bj = bcomp[cc];
      float2 o;
      o.x = acc[j].x + d[j * 2 + 0] + bj;
      o.y = acc[j].y + d[j * 2 + 1] + bj;
      *(float2*)(cx + ((size_t)b * CC + cc) * HW_IN + p) = o;
    }
  }
}

// 3x3 stride-2 conv, LDS-staged: 1024 blocks = [ph(16)][b(4)][hog(16)].
// Block: 4 out rows x 64 cols, 4 ci. LDS 19.1 KB -> 4 blocks/CU resident.
__global__ __launch_bounds__(256) void encoder_kernel(
    const float* __restrict__ wsr, float* __restrict__ part) {
  __shared__ float lds[4][9][136];   // 19.1 KB
  const float* cx   = wsr + OFF_CX;
  const float* wall = wsr + OFF_WE;
  int gb = blockIdx.x;
  int hog = gb & 15, b = (gb >> 4) & 3, ph = gb >> 6;
  int tid = threadIdx.x;
  int ci0 = ph * 4;
  int hi0 = hog * 8 - 1;             // first input row of the 9-row band

  for (int i = tid; i < 144; i += 256) {   // zero left halo (cols 0..3)
    int ci = i / 36; int r = (i % 36) >> 2; int j = i & 3;
    lds[ci][r][j] = 0.f;
  }
  for (int i = tid; i < 1152; i += 256) {  // interior
    int ci = i / 288; int r2 = i - ci * 288;
    int row = r2 >> 5, c4 = r2 & 31;
    int hi = hi0 + row;
    float4 v = make_float4(0.f, 0.f, 0.f, 0.f);
    if ((unsigned)hi < 128u)
      v = *(const float4*)(cx + ((size_t)(b * CC + ci0 + ci) * HW_IN) + hi * W_IN + c4 * 4);
    *(float4*)(&lds[ci][row][4 + c4 * 4]) = v;
  }
  __syncthreads();

  int wo = tid & 63, hs = tid >> 6;   // ho = hog*4+hs
  float acc[41];
#pragma unroll
  for (int ch = 0; ch < 41; ++ch) acc[ch] = 0.f;
  const float* lp = &lds[0][2 * hs][3 + 2 * wo];  // taps at imm offsets
#pragma unroll
  for (int ci = 0; ci < 4; ++ci) {
#pragma unroll
    for (int k3 = 0; k3 < 3; ++k3) {
#pragma unroll
      for (int kw = 0; kw < 3; ++kw) {
        float v = lp[ci * 1224 + k3 * 136 + kw];
        const float* w = wall + ((ci0 + ci) * 9 + k3 * 3 + kw) * 48;  // uniform
#pragma unroll
        for (int ch = 0; ch < 41; ++ch) acc[ch] = fmaf(w[ch], v, acc[ch]);
      }
    }
  }
  int px = b * HWO + (hog * 4 + hs) * 64 + wo;
  float* pb = part + (size_t)ph * NCHP * NPX + px;
#pragma unroll
  for (int ch = 0; ch < 41; ++ch) pb[(size_t)ch * NPX] = acc[ch];
}

// elementwise 16-phase reduce: thread = (ch, px-quad), fully coalesced float4
__global__ __launch_bounds__(256) void reduce_kernel(
    const float* __restrict__ wsr, float* __restrict__ red) {
  const float* part = wsr + OFF_PART;
  int i = blockIdx.x * 256 + threadIdx.x;   // 41*4096 = 167936 threads
  int ch = i >> 12, p4 = i & 4095;
  size_t off = (size_t)ch * NPX + p4 * 4;
  float4 s = make_float4(0.f, 0.f, 0.f, 0.f);
#pragma unroll
  for (int ph = 0; ph < NPH; ++ph) {
    float4 v = *(const float4*)(part + (size_t)ph * NCHP * NPX + off);
    s.x += v.x; s.y += v.y; s.z += v.z; s.w += v.w;
  }
  *(float4*)(red + off) = s;
}

// bias + temperature + softmax over 25 -> mask[k][px]; reads reduced[ch][px]
__global__ __launch_bounds__(64) void softmax_kernel(
    const float* __restrict__ wsr, const float* __restrict__ benc,
    const float* __restrict__ bkenc, float* __restrict__ mask) {
  const float* red = wsr + OFF_RED;
  int px = blockIdx.x * 64 + threadIdx.x;   // 16384 threads
  float lg[41];
#pragma unroll
  for (int ch = 0; ch < 41; ++ch) {
    float b = (ch < 25) ? benc[ch] : bkenc[ch - 25];
    lg[ch] = b + red[(size_t)ch * NPX + px];
  }
  float prod = lg[25];
#pragma unroll
  for (int ch = 26; ch < 41; ++ch) prod *= lg[ch];
  float iv = fminf(fmaxf(prod, -10.f), 10.f);
  float m = -1e30f;
#pragma unroll
  for (int ch = 0; ch < 25; ++ch) { lg[ch] *= iv; m = fmaxf(m, lg[ch]); }
  float sum = 0.f;
#pragma unroll
  for (int ch = 0; ch < 25; ++ch) { lg[ch] = __expf(lg[ch] - m); sum += lg[ch]; }
  float inv = 1.0f / sum;
#pragma unroll
  for (int ch = 0; ch < 25; ++ch)
    mask[(size_t)ch * NPX + px] = lg[ch] * inv;
}

// LDS-staged reassembly: block = [b(4)][hog(16)][cg(64 x 4ch)], 4096 blocks.
__global__ __launch_bounds__(256) void reassemble_kernel(
    const float* __restrict__ x, const float* __restrict__ wsr,
    float* __restrict__ out) {
  __shared__ float lds[4][11][136];    // 23.9 KB
  const float* mask = wsr + OFF_MASK;
  int tid = threadIdx.x;
  int gb = blockIdx.x;
  int cg = gb & 63, hog = (gb >> 6) & 15, b = gb >> 10;
  int hi0 = hog * 8 - 2;

  for (int i = tid; i < 352; i += 256) {
    int ch = i / 88; int r = i - ch * 88; int row = r >> 3; int p = r & 7;
    int idx = (p < 4) ? p : (128 + p);
    lds[ch][row][idx] = 0.f;
  }
  for (int i = tid; i < 1408; i += 256) {
    int ch = i / 352; int r = i - ch * 352;
    int row = r >> 5, c4 = r & 31;
    int hi = hi0 + row;
    float4 v = make_float4(0.f, 0.f, 0.f, 0.f);
    if ((unsigned)hi < 128u) {
      int c = cg * 4 + ch;
      v = *(const float4*)(x + ((size_t)(b * C_IN + c) * HW_IN) + hi * W_IN + c4 * 4);
    }
    *(float4*)(&lds[ch][row][4 + c4 * 4]) = v;
  }
  __syncthreads();

  int wo = tid & 63, hs = tid >> 6;
  int ho = hog * 4 + hs;
  int opix = ho * WO + wo;
  int gpx = b * HWO + opix;
  float mk[25];
#pragma unroll
  for (int k = 0; k < 25; ++k)
    mk[k] = mask[(size_t)k * NPX + gpx];
#pragma unroll
  for (int ch = 0; ch < 4; ++ch) {
    const float* lp = &lds[ch][2 * hs][2 + 2 * wo];
    float s = 0.f;
#pragma unroll
    for (int kh = 0; kh < 5; ++kh)
#pragma unroll
      for (int kw = 0; kw < 5; ++kw)
        s = fmaf(mk[kh * 5 + kw], lp[kh * 136 + kw], s);
    int c = cg * 4 + ch;
    out[(size_t)(b * C_IN + c) * HWO + opix] = s;
  }
}

extern "C" void kernel_launch(void* const* d_in, const int* in_sizes, int n_in,
                              void* d_out, int out_size, void* d_ws, size_t ws_size,
                              hipStream_t stream) {
  const float* x      = (const float*)d_in[0];
  const float* w_comp = (const float*)d_in[1];
  const float* b_comp = (const float*)d_in[2];
  const float* w_enc  = (const float*)d_in[3];
  const float* b_enc  = (const float*)d_in[4];
  const float* w_kenc = (const float*)d_in[5];
  const float* b_kenc = (const float*)d_in[6];
  float* ws  = (float*)d_ws;
  float* out = (float*)d_out;

  prep_kernel<<<172, 256, 0, stream>>>(w_comp, w_enc, w_kenc, ws);
  compress_kernel<<<512, 1024, 0, stream>>>(x, b_comp, ws, ws + OFF_CX);
  encoder_kernel<<<1024, 256, 0, stream>>>(ws, ws + OFF_PART);
  reduce_kernel<<<656, 256, 0, stream>>>(ws, ws + OFF_RED);
  softmax_kernel<<<256, 64, 0, stream>>>(ws, b_enc, b_kenc, ws + OFF_MASK);
  reassemble_kernel<<<4096, 256, 0, stream>>>(x, ws, out);
}

// Round 9
// 182.471 us; speedup vs baseline: 1.0980x; 1.0980x over previous
//
#include <hip/hip_runtime.h>

#define H_IN   128
#define W_IN   128
#define HW_IN  16384
#define C_IN   256
#define CC     64
#define HO     64
#define WO     64
#define HWO    4096
#define NB     4
#define NPX    16384   // B*HWO output pixels
#define NCHP   48      // padded encoder out channels (25 mask + 16 kenc + 7 pad)
#define NPH    16      // encoder ci-phases (4 ci each)

// workspace layout (float element offsets)
#define OFF_WE    16384        // 576*48     = 27648     encoder W [ci*9+t][48ch]
#define OFF_CX    44032        // 4*64*16384 = 4194304
#define OFF_PART  4238336      // 16*48*16384 = 12582912  partials [ph][ch][px]
#define OFF_MASK  16821248     // 25*16384   = 409600    mask [k][px]
#define OFF_RED   17230848     // 48*16384   = 786432    reduced [ch][px]
// total 18017280 floats = 72.1 MB

// 1x1 conv as GEMM, grid 512 = [pxblk(256)][ccHalf(2)].
// Block 512 = 4 ccg x 2 kh. Thread = 4 px (float4) x 8 cc, K=128.
// Depth-2 rotating prefetch; weights via wave-uniform s_loads from w_comp.
// Also folds the encoder-weight transform (54 els/block) -> kills prep kernel.
__global__ __launch_bounds__(512) void compress_kernel(
    const float* __restrict__ x, const float* __restrict__ wc,
    const float* __restrict__ bcomp, const float* __restrict__ we,
    const float* __restrict__ wk, float* __restrict__ ws) {
  int gb = blockIdx.x, tid = threadIdx.x;
  // ---- folded prep: encoder weights [ci*9+t][48] (512*54 = 27648 exactly)
  if (tid < 54) {
    int e = gb * 54 + tid;
    int row = e / 48, ch = e - row * 48;
    float v = 0.f;
    if (ch < 25)      v = we[ch * 576 + row];
    else if (ch < 41) v = wk[(ch - 25) * 576 + row];
    ws[OFF_WE + e] = v;
  }
  // ---- GEMM
  __shared__ float red[4][64][33];   // 33.8 KB, odd stride -> conflict-free
  int wv = tid >> 6, lane = tid & 63;
  int ccg = __builtin_amdgcn_readfirstlane(wv & 3);
  int kh  = __builtin_amdgcn_readfirstlane(wv >> 2);
  int ccw = gb & 1;
  int pxb = gb >> 1;                 // 0..255, 256 px each
  int b = pxb >> 6;
  int p = (pxb & 63) * 256 + lane * 4;
  int cc0 = ccw * 32 + ccg * 8;
  const float* xb = x + (size_t)b * C_IN * HW_IN + p;
  int cbase = kh * 128;
  float4 acc[8];
#pragma unroll
  for (int j = 0; j < 8; ++j) acc[j] = make_float4(0.f, 0.f, 0.f, 0.f);
  float4 xa[4], xc[4];
#pragma unroll
  for (int u = 0; u < 4; ++u)
    xa[u] = *(const float4*)(xb + (size_t)(cbase + u) * HW_IN);
#pragma unroll
  for (int u = 0; u < 4; ++u)
    xc[u] = *(const float4*)(xb + (size_t)(cbase + 4 + u) * HW_IN);
  for (int c0 = 0; c0 < 128; c0 += 8) {
    // compute on xa (c = cbase+c0+0..3), refill xa from c0+8
#pragma unroll
    for (int u = 0; u < 4; ++u) {
      float4 xu = xa[u];
#pragma unroll
      for (int j = 0; j < 8; ++j) {
        float wj = wc[(size_t)(cc0 + j) * C_IN + cbase + c0 + u];  // s_load
        acc[j].x = fmaf(wj, xu.x, acc[j].x);
        acc[j].y = fmaf(wj, xu.y, acc[j].y);
        acc[j].z = fmaf(wj, xu.z, acc[j].z);
        acc[j].w = fmaf(wj, xu.w, acc[j].w);
      }
    }
    if (c0 + 8 < 128) {
#pragma unroll
      for (int u = 0; u < 4; ++u)
        xa[u] = *(const float4*)(xb + (size_t)(cbase + c0 + 8 + u) * HW_IN);
    }
    // compute on xc (c = cbase+c0+4..7), refill xc from c0+12
#pragma unroll
    for (int u = 0; u < 4; ++u) {
      float4 xu = xc[u];
#pragma unroll
      for (int j = 0; j < 8; ++j) {
        float wj = wc[(size_t)(cc0 + j) * C_IN + cbase + c0 + 4 + u];
        acc[j].x = fmaf(wj, xu.x, acc[j].x);
        acc[j].y = fmaf(wj, xu.y, acc[j].y);
        acc[j].z = fmaf(wj, xu.z, acc[j].z);
        acc[j].w = fmaf(wj, xu.w, acc[j].w);
      }
    }
    if (c0 + 12 < 128) {
#pragma unroll
      for (int u = 0; u < 4; ++u)
        xc[u] = *(const float4*)(xb + (size_t)(cbase + c0 + 12 + u) * HW_IN);
    }
  }
  if (kh == 1) {
    float* d = &red[ccg][lane][0];
#pragma unroll
    for (int j = 0; j < 8; ++j) {
      d[j * 4 + 0] = acc[j].x; d[j * 4 + 1] = acc[j].y;
      d[j * 4 + 2] = acc[j].z; d[j * 4 + 3] = acc[j].w;
    }
  }
  __syncthreads();
  if (kh == 0) {
    float* cx = ws + OFF_CX;
    const float* d = &red[ccg][lane][0];
#pragma unroll
    for (int j = 0; j < 8; ++j) {
      int cc = cc0 + j;
      float bj = bcomp[cc];
      float4 o;
      o.x = acc[j].x + d[j * 4 + 0] + bj;
      o.y = acc[j].y + d[j * 4 + 1] + bj;
      o.z = acc[j].z + d[j * 4 + 2] + bj;
      o.w = acc[j].w + d[j * 4 + 3] + bj;
      *(float4*)(cx + ((size_t)b * CC + cc) * HW_IN + p) = o;
    }
  }
}

// 3x3 stride-2 conv, LDS-staged: 1024 blocks = [ph(16)][b(4)][hog(16)].
__global__ __launch_bounds__(256) void encoder_kernel(
    const float* __restrict__ wsr, float* __restrict__ part) {
  __shared__ float lds[4][9][136];   // 19.1 KB
  const float* cx   = wsr + OFF_CX;
  const float* wall = wsr + OFF_WE;
  int gb = blockIdx.x;
  int hog = gb & 15, b = (gb >> 4) & 3, ph = gb >> 6;
  int tid = threadIdx.x;
  int ci0 = ph * 4;
  int hi0 = hog * 8 - 1;             // first input row of the 9-row band

  for (int i = tid; i < 144; i += 256) {   // zero left halo (cols 0..3)
    int ci = i / 36; int r = (i % 36) >> 2; int j = i & 3;
    lds[ci][r][j] = 0.f;
  }
  for (int i = tid; i < 1152; i += 256) {  // interior
    int ci = i / 288; int r2 = i - ci * 288;
    int row = r2 >> 5, c4 = r2 & 31;
    int hi = hi0 + row;
    float4 v = make_float4(0.f, 0.f, 0.f, 0.f);
    if ((unsigned)hi < 128u)
      v = *(const float4*)(cx + ((size_t)(b * CC + ci0 + ci) * HW_IN) + hi * W_IN + c4 * 4);
    *(float4*)(&lds[ci][row][4 + c4 * 4]) = v;
  }
  __syncthreads();

  int wo = tid & 63, hs = tid >> 6;   // ho = hog*4+hs
  float acc[41];
#pragma unroll
  for (int ch = 0; ch < 41; ++ch) acc[ch] = 0.f;
  const float* lp = &lds[0][2 * hs][3 + 2 * wo];  // taps at imm offsets
#pragma unroll
  for (int ci = 0; ci < 4; ++ci) {
#pragma unroll
    for (int k3 = 0; k3 < 3; ++k3) {
#pragma unroll
      for (int kw = 0; kw < 3; ++kw) {
        float v = lp[ci * 1224 + k3 * 136 + kw];
        const float* w = wall + ((ci0 + ci) * 9 + k3 * 3 + kw) * 48;  // uniform
#pragma unroll
        for (int ch = 0; ch < 41; ++ch) acc[ch] = fmaf(w[ch], v, acc[ch]);
      }
    }
  }
  int px = b * HWO + (hog * 4 + hs) * 64 + wo;
  float* pb = part + (size_t)ph * NCHP * NPX + px;
#pragma unroll
  for (int ch = 0; ch < 41; ++ch) pb[(size_t)ch * NPX] = acc[ch];
}

// elementwise 16-phase reduce: thread = (ch, px-quad), fully coalesced float4
__global__ __launch_bounds__(256) void reduce_kernel(
    const float* __restrict__ wsr, float* __restrict__ red) {
  const float* part = wsr + OFF_PART;
  int i = blockIdx.x * 256 + threadIdx.x;   // 41*4096 = 167936 threads
  int ch = i >> 12, p4 = i & 4095;
  size_t off = (size_t)ch * NPX + p4 * 4;
  float4 s = make_float4(0.f, 0.f, 0.f, 0.f);
#pragma unroll
  for (int ph = 0; ph < NPH; ++ph) {
    float4 v = *(const float4*)(part + (size_t)ph * NCHP * NPX + off);
    s.x += v.x; s.y += v.y; s.z += v.z; s.w += v.w;
  }
  *(float4*)(red + off) = s;
}

// bias + temperature + softmax over 25 -> mask[k][px]; reads reduced[ch][px]
__global__ __launch_bounds__(64) void softmax_kernel(
    const float* __restrict__ wsr, const float* __restrict__ benc,
    const float* __restrict__ bkenc, float* __restrict__ mask) {
  const float* red = wsr + OFF_RED;
  int px = blockIdx.x * 64 + threadIdx.x;   // 16384 threads
  float lg[41];
#pragma unroll
  for (int ch = 0; ch < 41; ++ch) {
    float b = (ch < 25) ? benc[ch] : bkenc[ch - 25];
    lg[ch] = b + red[(size_t)ch * NPX + px];
  }
  float prod = lg[25];
#pragma unroll
  for (int ch = 26; ch < 41; ++ch) prod *= lg[ch];
  float iv = fminf(fmaxf(prod, -10.f), 10.f);
  float m = -1e30f;
#pragma unroll
  for (int ch = 0; ch < 25; ++ch) { lg[ch] *= iv; m = fmaxf(m, lg[ch]); }
  float sum = 0.f;
#pragma unroll
  for (int ch = 0; ch < 25; ++ch) { lg[ch] = __expf(lg[ch] - m); sum += lg[ch]; }
  float inv = 1.0f / sum;
#pragma unroll
  for (int ch = 0; ch < 25; ++ch)
    mask[(size_t)ch * NPX + px] = lg[ch] * inv;
}

// LDS-staged reassembly: block = [b(4)][hog(16)][cg(64 x 4ch)], 4096 blocks.
__global__ __launch_bounds__(256) void reassemble_kernel(
    const float* __restrict__ x, const float* __restrict__ wsr,
    float* __restrict__ out) {
  __shared__ float lds[4][11][136];    // 23.9 KB
  const float* mask = wsr + OFF_MASK;
  int tid = threadIdx.x;
  int gb = blockIdx.x;
  int cg = gb & 63, hog = (gb >> 6) & 15, b = gb >> 10;
  int hi0 = hog * 8 - 2;

  for (int i = tid; i < 352; i += 256) {
    int ch = i / 88; int r = i - ch * 88; int row = r >> 3; int p = r & 7;
    int idx = (p < 4) ? p : (128 + p);
    lds[ch][row][idx] = 0.f;
  }
  for (int i = tid; i < 1408; i += 256) {
    int ch = i / 352; int r = i - ch * 352;
    int row = r >> 5, c4 = r & 31;
    int hi = hi0 + row;
    float4 v = make_float4(0.f, 0.f, 0.f, 0.f);
    if ((unsigned)hi < 128u) {
      int c = cg * 4 + ch;
      v = *(const float4*)(x + ((size_t)(b * C_IN + c) * HW_IN) + hi * W_IN + c4 * 4);
    }
    *(float4*)(&lds[ch][row][4 + c4 * 4]) = v;
  }
  __syncthreads();

  int wo = tid & 63, hs = tid >> 6;
  int ho = hog * 4 + hs;
  int opix = ho * WO + wo;
  int gpx = b * HWO + opix;
  float mk[25];
#pragma unroll
  for (int k = 0; k < 25; ++k)
    mk[k] = mask[(size_t)k * NPX + gpx];
#pragma unroll
  for (int ch = 0; ch < 4; ++ch) {
    const float* lp = &lds[ch][2 * hs][2 + 2 * wo];
    float s = 0.f;
#pragma unroll
    for (int kh = 0; kh < 5; ++kh)
#pragma unroll
      for (int kw = 0; kw < 5; ++kw)
        s = fmaf(mk[kh * 5 + kw], lp[kh * 136 + kw], s);
    int c = cg * 4 + ch;
    out[(size_t)(b * C_IN + c) * HWO + opix] = s;
  }
}

extern "C" void kernel_launch(void* const* d_in, const int* in_sizes, int n_in,
                              void* d_out, int out_size, void* d_ws, size_t ws_size,
                              hipStream_t stream) {
  const float* x      = (const float*)d_in[0];
  const float* w_comp = (const float*)d_in[1];
  const float* b_comp = (const float*)d_in[2];
  const float* w_enc  = (const float*)d_in[3];
  const float* b_enc  = (const float*)d_in[4];
  const float* w_kenc = (const float*)d_in[5];
  const float* b_kenc = (const float*)d_in[6];
  float* ws  = (float*)d_ws;
  float* out = (float*)d_out;

  compress_kernel<<<512, 512, 0, stream>>>(x, w_comp, b_comp, w_enc, w_kenc, ws);
  encoder_kernel<<<1024, 256, 0, stream>>>(ws, ws + OFF_PART);
  reduce_kernel<<<656, 256, 0, stream>>>(ws, ws + OFF_RED);
  softmax_kernel<<<256, 64, 0, stream>>>(ws, b_enc, b_kenc, ws + OFF_MASK);
  reassemble_kernel<<<4096, 256, 0, stream>>>(x, ws, out);
}